// Round 1
// baseline (17455.884 us; speedup 1.0000x reference)
//
#include <hip/hip_runtime.h>
#include <stdint.h>

#define T_SEQ 2048
#define NB 32
#define NH 1024
#define HH (NH*NH)
#define HIST_ELEMS ((size_t)T_SEQ*NB*NH)

typedef __attribute__((ext_vector_type(8))) short bf16x8;
typedef __attribute__((ext_vector_type(4))) float f32x4;
typedef __attribute__((ext_vector_type(4))) int   i32x4;
typedef __attribute__((ext_vector_type(2))) int   i32x2;
typedef __attribute__((ext_vector_type(4))) short s16x4;

__device__ __forceinline__ unsigned short bf16rne(float f){
  union { float f; unsigned u; } v; v.f = f;
  unsigned u = v.u;
  return (unsigned short)((u + 0x7FFFu + ((u >> 16) & 1u)) >> 16);
}
__device__ __forceinline__ float bf16tof(unsigned short s){
  union { unsigned u; float f; } v; v.u = ((unsigned)s) << 16; return v.f;
}
__device__ __forceinline__ float fast_tanh(float x){
  float ax = fabsf(x);
  float e  = __expf(-2.0f*ax);
  float t  = (1.0f - e) / (1.0f + e);
  return copysignf(t, x);
}

// ---- cross-XCD coherent (L1+L2 bypass) memory ops ----
__device__ __forceinline__ i32x4 ld128_cohere(const void* p){
  i32x4 d;
  asm volatile("global_load_dwordx4 %0, %1, off sc0 sc1" : "=v"(d) : "v"(p) : "memory");
  return d;
}
__device__ __forceinline__ void st64_cohere(void* p, i32x2 v){
  asm volatile("global_store_dwordx2 %0, %1, off sc0 sc1" :: "v"(p), "v"(v) : "memory");
}
__device__ __forceinline__ void st32_cohere(void* p, int v){
  asm volatile("global_store_dword %0, %1, off sc0 sc1" :: "v"(p), "v"(v) : "memory");
}
__device__ __forceinline__ void vmem_drain(){
  asm volatile("s_waitcnt vmcnt(0)" ::: "memory");
  __builtin_amdgcn_sched_barrier(0);   // rule-18: stop hoisting of reg-only uses above the wait
}

// =====================================================================
// Kernel 1: pre0[t*32+b][c] = sum_d x[t,b,d]*Wih0[c,d] + b_ih0[c] + b_hh0[c]
// x split hi/lo bf16 (2 MFMAs) for accuracy; output fp16.
// =====================================================================
__global__ __launch_bounds__(256)
void pre_gemm(const float* __restrict__ x,
              const float* __restrict__ Wih,
              const float* __restrict__ bih,
              const float* __restrict__ bhh,
              _Float16* __restrict__ pre0)
{
  __shared__ float As[128][36];          // 32k + pad -> 144B row stride (conflict-free-ish)
  const int tid  = threadIdx.x;
  const int lane = tid & 63;
  const int wave = tid >> 6;
  const int l15  = lane & 15;
  const int l4   = lane >> 4;
  const int n0   = blockIdx.x * 128;
  const int m0   = blockIdx.y * 128;
  const int qm   = wave >> 1;
  const int qn   = wave & 1;

  f32x4 acc[4][4];
  #pragma unroll
  for (int i = 0; i < 4; ++i)
    #pragma unroll
    for (int j = 0; j < 4; ++j) acc[i][j] = (f32x4){0.f,0.f,0.f,0.f};

  const int sr = tid >> 1;
  const int sh = tid & 1;
  const float* xrow = x + (size_t)(m0 + sr)*NH + sh*16;

  for (int kb = 0; kb < 32; ++kb){
    __syncthreads();
    {
      const float* src = xrow + kb*32;
      f32x4 v0 = *(const f32x4*)(src + 0);
      f32x4 v1 = *(const f32x4*)(src + 4);
      f32x4 v2 = *(const f32x4*)(src + 8);
      f32x4 v3 = *(const f32x4*)(src + 12);
      float* dst = &As[sr][sh*16];
      *(f32x4*)(dst + 0)  = v0;
      *(f32x4*)(dst + 4)  = v1;
      *(f32x4*)(dst + 8)  = v2;
      *(f32x4*)(dst + 12) = v3;
    }
    __syncthreads();

    bf16x8 ahi[4], alo[4];
    #pragma unroll
    for (int mt = 0; mt < 4; ++mt){
      const float* ap = &As[64*qm + 16*mt + l15][l4*8];
      #pragma unroll
      for (int j = 0; j < 8; ++j){
        float a = ap[j];
        unsigned short hb = bf16rne(a);
        ahi[mt][j] = (short)hb;
        alo[mt][j] = (short)bf16rne(a - bf16tof(hb));
      }
    }
    #pragma unroll
    for (int nf = 0; nf < 4; ++nf){
      const int c = n0 + 64*qn + 16*nf + l15;
      const float* wp = Wih + (size_t)c*NH + kb*32 + l4*8;
      bf16x8 bf;
      #pragma unroll
      for (int j = 0; j < 8; ++j) bf[j] = (short)bf16rne(wp[j]);
      #pragma unroll
      for (int mt = 0; mt < 4; ++mt){
        acc[mt][nf] = __builtin_amdgcn_mfma_f32_16x16x32_bf16(ahi[mt], bf, acc[mt][nf], 0,0,0);
        acc[mt][nf] = __builtin_amdgcn_mfma_f32_16x16x32_bf16(alo[mt], bf, acc[mt][nf], 0,0,0);
      }
    }
  }

  #pragma unroll
  for (int nf = 0; nf < 4; ++nf){
    const int c = n0 + 64*qn + 16*nf + l15;
    const float bv = bih[c] + bhh[c];
    #pragma unroll
    for (int mt = 0; mt < 4; ++mt){
      const int mb = m0 + 64*qm + 16*mt + l4*4;
      #pragma unroll
      for (int j = 0; j < 4; ++j)
        pre0[(size_t)(mb + j)*NH + c] = (_Float16)(acc[mt][nf][j] + bv);
    }
  }
}

// =====================================================================
// Kernel 2: persistent recurrence. 64 WGs x 256 threads.
// WG w owns output cols [16w,16w+16) of BOTH layers.
// Phase p: compute h0(p) (if p<T) and h1(p-1) (if p>=1), both from
// phase-(p-1) state. Weights = static VGPR A-frags; state gathered as
// B-frags with sc0/sc1; one flag-barrier per phase.
// =====================================================================
__global__ __launch_bounds__(256, 1)
void rnn_seq(const float* __restrict__ h0in,
             const float* __restrict__ Wih,
             const float* __restrict__ Whh,
             const float* __restrict__ bih,
             const float* __restrict__ bhh,
             const _Float16* __restrict__ pre0,
             float* __restrict__ dout,
             char* __restrict__ ws)
{
  const int wg   = blockIdx.x;    // 0..63
  const int tid  = threadIdx.x;   // 0..255
  const int lane = tid & 63;
  const int wave = tid >> 6;      // K-slice owner: k in [256*wave, 256*wave+256)
  const int l15  = lane & 15;
  const int l4   = lane >> 4;
  const int c0   = wg * 16;

  int*  flags = (int*)ws;               // 64 ints, memset to 0 per launch
  char* h0buf = ws + 4096;              // [2][32][1024] bf16 (double-buffered)
  char* h1buf = ws + 4096 + 131072;

  // ---- static weight A-fragments in registers: [0]=Whh0 [1]=Wih1 [2]=Whh1 ----
  bf16x8 wA[3][8];
  {
    const size_t row = (size_t)(c0 + l15) * NH;
    const float* s0 = Whh + row;
    const float* s1 = Wih + HH + row;
    const float* s2 = Whh + HH + row;
    #pragma unroll
    for (int s = 0; s < 8; ++s){
      const int k = wave*256 + s*32 + l4*8;
      #pragma unroll
      for (int j = 0; j < 8; ++j){
        wA[0][s][j] = (short)bf16rne(s0[k+j]);
        wA[1][s][j] = (short)bf16rne(s1[k+j]);
        wA[2][s][j] = (short)bf16rne(s2[k+j]);
      }
    }
  }

  // ---- epilogue mapping: thread -> (layer, batch, 4-col block) ----
  const int elayer = tid >> 7;
  const int eb     = (tid >> 2) & 31;
  const int ecb    = tid & 3;
  const int ecol   = c0 + ecb*4;

  f32x4 bias1 = {0.f,0.f,0.f,0.f};
  if (elayer == 1){
    #pragma unroll
    for (int j = 0; j < 4; ++j)
      bias1[j] = bih[NH + ecol + j] + bhh[NH + ecol + j];
  }

  // ---- initial state h(-1) -> parity-1 buffers ----
  {
    const float* hs = h0in + (size_t)elayer*NB*NH + (size_t)eb*NH + ecol;
    i32x2 pk;
    pk[0] = (int)bf16rne(hs[0]) | ((int)bf16rne(hs[1]) << 16);
    pk[1] = (int)bf16rne(hs[2]) | ((int)bf16rne(hs[3]) << 16);
    char* dst = (elayer == 0 ? h0buf : h1buf) + 65536 + eb*2048 + ecol*2;
    st64_cohere(dst, pk);
  }
  vmem_drain();
  __syncthreads();
  if (tid == 0) st32_cohere(flags + wg, 1);   // init published

  __shared__ float scr[4][4][16][16];   // [wave][frag: h0bt0,h0bt1,h1bt0,h1bt1][bl][cl]
  long spins = 0;

  for (int p = 0; p <= T_SEQ; ++p){
    const bool doL0 = (p < T_SEQ);
    const bool doL1 = (p >= 1);

    // prefetch pre0 slice (independent of flags; consumed in epilogue)
    s16x4 praw = {0,0,0,0};
    if (elayer == 0 && doL0)
      praw = *(const s16x4*)(pre0 + (size_t)p*(NB*NH) + (size_t)eb*NH + ecol);

    // ---- wait: all 64 WGs finished phase p-1 (flag >= 1+p) ----
    {
      const int target = 1 + p;
      const int* fp = flags + (l15 << 2);    // lanes cover all 64 flags
      for (;;){
        i32x4 f = ld128_cohere(fp);
        vmem_drain();
        int ok = (f[0] >= target) && (f[1] >= target) && (f[2] >= target) && (f[3] >= target);
        if (__all(ok)) break;
        if (++spins > (1L << 22)) break;     // safety valve: never hang
        __builtin_amdgcn_s_sleep(2);
      }
    }

    // ---- gather state B-fragments (coherent, bypass L1/L2) ----
    const char* h0rd = h0buf + ((p-1)&1)*65536;
    const char* h1rd = h1buf + ((p-2)&1)*65536;
    i32x4 g0[2][8], g1[2][8];
    #pragma unroll
    for (int bt = 0; bt < 2; ++bt){
      const int b = bt*16 + l15;
      #pragma unroll
      for (int s = 0; s < 8; ++s){
        const int d = wave*256 + s*32 + l4*8;
        g0[bt][s] = ld128_cohere(h0rd + b*2048 + d*2);
      }
    }
    if (doL1){
      #pragma unroll
      for (int bt = 0; bt < 2; ++bt){
        const int b = bt*16 + l15;
        #pragma unroll
        for (int s = 0; s < 8; ++s){
          const int d = wave*256 + s*32 + l4*8;
          g1[bt][s] = ld128_cohere(h1rd + b*2048 + d*2);
        }
      }
    }
    vmem_drain();

    // ---- MFMA partial sums over this wave's K-slice ----
    f32x4 acc0[2] = {{0,0,0,0},{0,0,0,0}};
    f32x4 acc1[2] = {{0,0,0,0},{0,0,0,0}};
    #pragma unroll
    for (int bt = 0; bt < 2; ++bt){
      #pragma unroll
      for (int s = 0; s < 8; ++s){
        bf16x8 b0 = __builtin_bit_cast(bf16x8, g0[bt][s]);
        if (doL0)
          acc0[bt] = __builtin_amdgcn_mfma_f32_16x16x32_bf16(wA[0][s], b0, acc0[bt], 0,0,0);
        if (doL1){
          acc1[bt] = __builtin_amdgcn_mfma_f32_16x16x32_bf16(wA[1][s], b0, acc1[bt], 0,0,0);
          bf16x8 b1 = __builtin_bit_cast(bf16x8, g1[bt][s]);
          acc1[bt] = __builtin_amdgcn_mfma_f32_16x16x32_bf16(wA[2][s], b1, acc1[bt], 0,0,0);
        }
      }
    }

    // ---- cross-wave K reduction via LDS ----
    *(f32x4*)&scr[wave][0][l15][l4*4] = acc0[0];
    *(f32x4*)&scr[wave][1][l15][l4*4] = acc0[1];
    *(f32x4*)&scr[wave][2][l15][l4*4] = acc1[0];
    *(f32x4*)&scr[wave][3][l15][l4*4] = acc1[1];
    __syncthreads();

    f32x4 sum = {0,0,0,0};
    {
      const int f = elayer*2 + (eb >> 4);
      #pragma unroll
      for (int w = 0; w < 4; ++w)
        sum += *(const f32x4*)&scr[w][f][eb & 15][ecb*4];
    }

    if (elayer == 0){
      if (doL0){
        union { s16x4 v; _Float16 h[4]; } pu; pu.v = praw;
        float hv[4];
        #pragma unroll
        for (int j = 0; j < 4; ++j)
          hv[j] = fast_tanh(sum[j] + (float)pu.h[j]);
        i32x2 pk;
        pk[0] = (int)bf16rne(hv[0]) | ((int)bf16rne(hv[1]) << 16);
        pk[1] = (int)bf16rne(hv[2]) | ((int)bf16rne(hv[3]) << 16);
        st64_cohere(h0buf + (p&1)*65536 + eb*2048 + ecol*2, pk);
        if (p == T_SEQ-1){
          f32x4 o = {hv[0], hv[1], hv[2], hv[3]};
          *(f32x4*)(dout + HIST_ELEMS + (size_t)eb*NH + ecol) = o;   // h_T layer0
        }
      }
    } else {
      if (doL1){
        float hv[4];
        #pragma unroll
        for (int j = 0; j < 4; ++j)
          hv[j] = fast_tanh(sum[j] + bias1[j]);
        i32x2 pk;
        pk[0] = (int)bf16rne(hv[0]) | ((int)bf16rne(hv[1]) << 16);
        pk[1] = (int)bf16rne(hv[2]) | ((int)bf16rne(hv[3]) << 16);
        st64_cohere(h1buf + ((p-1)&1)*65536 + eb*2048 + ecol*2, pk);
        f32x4 o = {hv[0], hv[1], hv[2], hv[3]};
        *(f32x4*)(dout + (size_t)(p-1)*(NB*NH) + (size_t)eb*NH + ecol) = o;  // history
        if (p == T_SEQ)
          *(f32x4*)(dout + HIST_ELEMS + (size_t)NB*NH + (size_t)eb*NH + ecol) = o; // h_T layer1
      }
    }

    vmem_drain();        // each wave's sc-stores complete
    __syncthreads();     // all waves' stores complete
    if (tid == 0) st32_cohere(flags + wg, 2 + p);
  }
}

extern "C" void kernel_launch(void* const* d_in, const int* in_sizes, int n_in,
                              void* d_out, int out_size, void* d_ws, size_t ws_size,
                              hipStream_t stream)
{
  (void)in_sizes; (void)n_in; (void)out_size;
  const float* x   = (const float*)d_in[0];
  const float* h0  = (const float*)d_in[1];
  const float* Wih = (const float*)d_in[2];
  const float* Whh = (const float*)d_in[3];
  const float* bih = (const float*)d_in[4];
  const float* bhh = (const float*)d_in[5];
  float* out = (float*)d_out;
  char*  ws  = (char*)d_ws;

  const size_t PRE0_OFF = (size_t)1 << 20;
  const size_t NEED = PRE0_OFF + (size_t)T_SEQ*NB*NH*sizeof(_Float16);
  if (ws_size < NEED) return;   // clean failure signal if scratch too small

  _Float16* pre0 = (_Float16*)(ws + PRE0_OFF);

  hipMemsetAsync(ws, 0, 4096, stream);                       // reset flags (capturable)
  pre_gemm<<<dim3(8, 512), 256, 0, stream>>>(x, Wih, bih, bhh, pre0);
  rnn_seq<<<dim3(64), 256, 0, stream>>>(h0, Wih, Whh, bih, bhh, pre0, out, ws);
}

// Round 3
// 15418.478 us; speedup vs baseline: 1.1321x; 1.1321x over previous
//
#include <hip/hip_runtime.h>
#include <stdint.h>

#define T_SEQ 2048
#define NB 32
#define NH 1024
#define HH (NH*NH)
#define HIST_ELEMS ((size_t)T_SEQ*NB*NH)
#define TEAM 32

typedef __attribute__((ext_vector_type(8))) short bf16x8;
typedef __attribute__((ext_vector_type(4))) float f32x4;
typedef __attribute__((ext_vector_type(4))) int   i32x4;
typedef __attribute__((ext_vector_type(2))) int   i32x2;
typedef __attribute__((ext_vector_type(4))) short s16x4;

__device__ __forceinline__ unsigned short bf16rne(float f){
  union { float f; unsigned u; } v; v.f = f;
  unsigned u = v.u;
  return (unsigned short)((u + 0x7FFFu + ((u >> 16) & 1u)) >> 16);
}
__device__ __forceinline__ float bf16tof(unsigned short s){
  union { unsigned u; float f; } v; v.u = ((unsigned)s) << 16; return v.f;
}
__device__ __forceinline__ float fast_tanh(float x){
  float ax = fabsf(x);
  float e  = __expf(-2.0f*ax);
  float t  = (1.0f - e) / (1.0f + e);
  return copysignf(t, x);
}

// ---- device-scope coherent ops (sc0 sc1 — PROVEN on this chip in R1) ----
__device__ __forceinline__ i32x4 ld128_c(const void* p){
  i32x4 d;
  asm volatile("global_load_dwordx4 %0, %1, off sc0 sc1" : "=v"(d) : "v"(p) : "memory");
  return d;
}
__device__ __forceinline__ void st64_c(void* p, i32x2 v){
  asm volatile("global_store_dwordx2 %0, %1, off sc0 sc1" :: "v"(p), "v"(v) : "memory");
}
__device__ __forceinline__ void st32_c(void* p, unsigned v){
  asm volatile("global_store_dword %0, %1, off sc0 sc1" :: "v"(p), "v"(v) : "memory");
}
__device__ __forceinline__ unsigned ld32_c(const void* p){
  unsigned d;
  asm volatile("global_load_dword %0, %1, off sc0 sc1\n\ts_waitcnt vmcnt(0)"
               : "=v"(d) : "v"(p) : "memory");
  __builtin_amdgcn_sched_barrier(0);
  return d;
}
__device__ __forceinline__ void vmem_drain(){
  asm volatile("s_waitcnt vmcnt(0)" ::: "memory");
  __builtin_amdgcn_sched_barrier(0);
}

// =====================================================================
// Kernel 1: pre0[t*32+b][c] = sum_d x[t,b,d]*Wih0[c,d] + b_ih0[c] + b_hh0[c]
// (unchanged — validated in R1)
// =====================================================================
__global__ __launch_bounds__(256)
void pre_gemm(const float* __restrict__ x,
              const float* __restrict__ Wih,
              const float* __restrict__ bih,
              const float* __restrict__ bhh,
              _Float16* __restrict__ pre0)
{
  __shared__ float As[128][36];
  const int tid  = threadIdx.x;
  const int lane = tid & 63;
  const int wave = tid >> 6;
  const int l15  = lane & 15;
  const int l4   = lane >> 4;
  const int n0   = blockIdx.x * 128;
  const int m0   = blockIdx.y * 128;
  const int qm   = wave >> 1;
  const int qn   = wave & 1;

  f32x4 acc[4][4];
  #pragma unroll
  for (int i = 0; i < 4; ++i)
    #pragma unroll
    for (int j = 0; j < 4; ++j) acc[i][j] = (f32x4){0.f,0.f,0.f,0.f};

  const int sr = tid >> 1;
  const int sh = tid & 1;
  const float* xrow = x + (size_t)(m0 + sr)*NH + sh*16;

  for (int kb = 0; kb < 32; ++kb){
    __syncthreads();
    {
      const float* src = xrow + kb*32;
      f32x4 v0 = *(const f32x4*)(src + 0);
      f32x4 v1 = *(const f32x4*)(src + 4);
      f32x4 v2 = *(const f32x4*)(src + 8);
      f32x4 v3 = *(const f32x4*)(src + 12);
      float* dst = &As[sr][sh*16];
      *(f32x4*)(dst + 0)  = v0;
      *(f32x4*)(dst + 4)  = v1;
      *(f32x4*)(dst + 8)  = v2;
      *(f32x4*)(dst + 12) = v3;
    }
    __syncthreads();

    bf16x8 ahi[4], alo[4];
    #pragma unroll
    for (int mt = 0; mt < 4; ++mt){
      const float* ap = &As[64*qm + 16*mt + l15][l4*8];
      #pragma unroll
      for (int j = 0; j < 8; ++j){
        float a = ap[j];
        unsigned short hb = bf16rne(a);
        ahi[mt][j] = (short)hb;
        alo[mt][j] = (short)bf16rne(a - bf16tof(hb));
      }
    }
    #pragma unroll
    for (int nf = 0; nf < 4; ++nf){
      const int c = n0 + 64*qn + 16*nf + l15;
      const float* wp = Wih + (size_t)c*NH + kb*32 + l4*8;
      bf16x8 bf;
      #pragma unroll
      for (int j = 0; j < 8; ++j) bf[j] = (short)bf16rne(wp[j]);
      #pragma unroll
      for (int mt = 0; mt < 4; ++mt){
        acc[mt][nf] = __builtin_amdgcn_mfma_f32_16x16x32_bf16(ahi[mt], bf, acc[mt][nf], 0,0,0);
        acc[mt][nf] = __builtin_amdgcn_mfma_f32_16x16x32_bf16(alo[mt], bf, acc[mt][nf], 0,0,0);
      }
    }
  }

  #pragma unroll
  for (int nf = 0; nf < 4; ++nf){
    const int c = n0 + 64*qn + 16*nf + l15;
    const float bv = bih[c] + bhh[c];
    #pragma unroll
    for (int mt = 0; mt < 4; ++mt){
      const int mb = m0 + 64*qm + 16*mt + l4*4;
      #pragma unroll
      for (int j = 0; j < 4; ++j)
        pre0[(size_t)(mb + j)*NH + c] = (_Float16)(acc[mt][nf][j] + bv);
    }
  }
}

// =====================================================================
// Kernel 2: single-XCD persistent recurrence (32 WGs, elected at runtime).
// All cross-WG traffic device-scope (sc0 sc1). Flags epoch-monotonic.
// =====================================================================
__global__ __launch_bounds__(256, 1)
void rnn_seq(const float* __restrict__ h0in,
             const float* __restrict__ Wih,
             const float* __restrict__ Whh,
             const float* __restrict__ bih,
             const float* __restrict__ bhh,
             const _Float16* __restrict__ pre0,
             float* __restrict__ dout,
             char* __restrict__ ws)
{
  const int tid  = threadIdx.x;
  const int lane = tid & 63;
  const int wave = tid >> 6;
  const int l15  = lane & 15;
  const int l4   = lane >> 4;

  unsigned* counts = (unsigned*)ws;            // [8]  (memset 0 each launch)
  unsigned* winner = (unsigned*)(ws + 64);     // 0=unset else xcc+1 (memset)
  unsigned* bcast  = (unsigned*)(ws + 128);    // [0]=base [1]=ready (memset)
  unsigned* flags  = (unsigned*)(ws + 4096);   // [32], NEVER reset (epoch)
  char* h0buf = ws + 8192;                     // [2][32][1024] bf16
  char* h1buf = ws + 8192 + 131072;

  __shared__ unsigned sh_go, sh_rank, sh_base;

  // ---------------- election (tid 0 only) ----------------
  if (tid == 0){
    unsigned xcc;
    asm volatile("s_getreg_b32 %0, hwreg(HW_REG_XCC_ID)" : "=s"(xcc));
    xcc &= 7u;
    unsigned slot = atomicAdd(&counts[xcc], 1u);
    unsigned go = 0, rank = 0, base = 0;
    if (slot < TEAM){
      if (slot == TEAM - 1) atomicCAS(winner, 0u, xcc + 1u);
      unsigned w = 0; long c = 0;
      for (;;){
        w = ld32_c(winner);
        if (w) break;
        if (++c > (1L << 20)) break;
        __builtin_amdgcn_s_sleep(8);
      }
      if (w == xcc + 1u){ go = 1; rank = slot; }
    }
    if (go){
      if (rank == 0){
        unsigned mx = 0;
        for (int i = 0; i < TEAM; ++i){ unsigned v = ld32_c(flags + i); if (v > mx) mx = v; }
        if (mx > 0xF0000000u) mx = 0;
        for (int i = 0; i < TEAM; ++i) st32_c(flags + i, mx);
        st32_c(bcast + 0, mx);
        vmem_drain();
        st32_c(bcast + 1, 1u);
        vmem_drain();
        base = mx;
      } else {
        long c = 0;
        for (;;){
          unsigned r = ld32_c(bcast + 1);
          if (r) break;
          if (++c > (1L << 23)) break;
          __builtin_amdgcn_s_sleep(2);
        }
        base = ld32_c(bcast + 0);
      }
    }
    sh_go = go; sh_rank = rank; sh_base = base;
  }
  __syncthreads();
  if (!sh_go) return;
  const unsigned rank = sh_rank;
  const unsigned base = sh_base;
  const int c0 = (int)rank * 32;

  // ---- static weight A-fragments: [0]=Whh0 [1]=Wih1 [2]=Whh1 ----
  bf16x8 wA[3][2][8];
  #pragma unroll
  for (int cf = 0; cf < 2; ++cf){
    const size_t row = (size_t)(c0 + cf*16 + l15) * NH;
    const float* s0 = Whh + row;
    const float* s1 = Wih + HH + row;
    const float* s2 = Whh + HH + row;
    #pragma unroll
    for (int s = 0; s < 8; ++s){
      const int k = wave*256 + s*32 + l4*8;
      #pragma unroll
      for (int j = 0; j < 8; ++j){
        wA[0][cf][s][j] = (short)bf16rne(s0[k+j]);
        wA[1][cf][s][j] = (short)bf16rne(s1[k+j]);
        wA[2][cf][s][j] = (short)bf16rne(s2[k+j]);
      }
    }
  }

  // ---- epilogue mapping: every thread owns one 4-col slot in BOTH layers ----
  const int eb   = tid >> 3;       // batch 0..31
  const int ecb  = tid & 7;        // col block 0..7
  const int ecol = c0 + ecb*4;

  f32x4 bias1;
  #pragma unroll
  for (int j = 0; j < 4; ++j)
    bias1[j] = bih[NH + ecol + j] + bhh[NH + ecol + j];

  // ---- initial state h(-1) -> parity-1 buffers ----
  {
    const float* hs0 = h0in + (size_t)eb*NH + ecol;
    const float* hs1 = h0in + (size_t)NB*NH + (size_t)eb*NH + ecol;
    i32x2 p0, p1;
    p0[0] = (int)bf16rne(hs0[0]) | ((int)bf16rne(hs0[1]) << 16);
    p0[1] = (int)bf16rne(hs0[2]) | ((int)bf16rne(hs0[3]) << 16);
    p1[0] = (int)bf16rne(hs1[0]) | ((int)bf16rne(hs1[1]) << 16);
    p1[1] = (int)bf16rne(hs1[2]) | ((int)bf16rne(hs1[3]) << 16);
    st64_c(h0buf + 65536 + eb*2048 + ecol*2, p0);
    st64_c(h1buf + 65536 + eb*2048 + ecol*2, p1);
  }
  vmem_drain();
  __syncthreads();
  if (tid == 0) st32_c(flags + rank, base + 1u);

  __shared__ float scr[4][8][16][20];   // padded: kills 8-way ds_write conflict
  long spins = 0;

  for (int p = 0; p <= T_SEQ; ++p){
    const bool doL0 = (p < T_SEQ);
    const bool doL1 = (p >= 1);

    // prefetch pre0 slice (normal cached load; overlaps the barrier wait)
    s16x4 praw = {0,0,0,0};
    if (doL0)
      praw = *(const s16x4*)(pre0 + (size_t)p*(NB*NH) + (size_t)eb*NH + ecol);

    // ---- flag barrier: wave 0 polls, others wait at syncthreads ----
    if (wave == 0){
      const unsigned target = base + 1u + (unsigned)p;
      const unsigned* fp = flags + ((lane & 7) << 2);
      for (;;){
        i32x4 f = ld128_c(fp);
        vmem_drain();
        int ok = ((unsigned)f[0] >= target) && ((unsigned)f[1] >= target)
              && ((unsigned)f[2] >= target) && ((unsigned)f[3] >= target);
        if (__all(ok)) break;
        if (++spins > (1L << 25)) break;
        __builtin_amdgcn_s_sleep(1);
      }
    }
    __syncthreads();

    // ---- gather state B-fragments (device-coherent) ----
    const char* h0rd = h0buf + ((p-1)&1)*65536;
    const char* h1rd = h1buf + ((p-2)&1)*65536;
    i32x4 g0[2][8], g1[2][8];
    #pragma unroll
    for (int bt = 0; bt < 2; ++bt){
      const int b = bt*16 + l15;
      #pragma unroll
      for (int s = 0; s < 8; ++s){
        const int d = wave*256 + s*32 + l4*8;
        g0[bt][s] = ld128_c(h0rd + b*2048 + d*2);
      }
    }
    if (doL1){
      #pragma unroll
      for (int bt = 0; bt < 2; ++bt){
        const int b = bt*16 + l15;
        #pragma unroll
        for (int s = 0; s < 8; ++s){
          const int d = wave*256 + s*32 + l4*8;
          g1[bt][s] = ld128_c(h1rd + b*2048 + d*2);
        }
      }
    }
    vmem_drain();

    // ---- MFMA partial sums over this wave's K-slice ----
    f32x4 acc0[2][2] = {{{0,0,0,0},{0,0,0,0}},{{0,0,0,0},{0,0,0,0}}};
    f32x4 acc1[2][2] = {{{0,0,0,0},{0,0,0,0}},{{0,0,0,0},{0,0,0,0}}};
    #pragma unroll
    for (int cf = 0; cf < 2; ++cf){
      #pragma unroll
      for (int bt = 0; bt < 2; ++bt){
        #pragma unroll
        for (int s = 0; s < 8; ++s){
          bf16x8 b0 = __builtin_bit_cast(bf16x8, g0[bt][s]);
          if (doL0)
            acc0[cf][bt] = __builtin_amdgcn_mfma_f32_16x16x32_bf16(wA[0][cf][s], b0, acc0[cf][bt], 0,0,0);
          if (doL1){
            acc1[cf][bt] = __builtin_amdgcn_mfma_f32_16x16x32_bf16(wA[1][cf][s], b0, acc1[cf][bt], 0,0,0);
            bf16x8 b1 = __builtin_bit_cast(bf16x8, g1[bt][s]);
            acc1[cf][bt] = __builtin_amdgcn_mfma_f32_16x16x32_bf16(wA[2][cf][s], b1, acc1[cf][bt], 0,0,0);
          }
        }
      }
    }

    // ---- cross-wave K reduction via LDS ----
    #pragma unroll
    for (int cf = 0; cf < 2; ++cf){
      #pragma unroll
      for (int bt = 0; bt < 2; ++bt){
        *(f32x4*)&scr[wave][(cf<<1)|bt][l15][l4*4]     = acc0[cf][bt];
        *(f32x4*)&scr[wave][4|(cf<<1)|bt][l15][l4*4]   = acc1[cf][bt];
      }
    }
    __syncthreads();

    const int fL0 = ((ecb >> 2) << 1) | (eb >> 4);
    f32x4 s0v = {0,0,0,0}, s1v = {0,0,0,0};
    #pragma unroll
    for (int w = 0; w < 4; ++w){
      s0v += *(const f32x4*)&scr[w][fL0][eb & 15][(ecb & 3)*4];
      s1v += *(const f32x4*)&scr[w][4|fL0][eb & 15][(ecb & 3)*4];
    }

    // ---- compute activations, store STATE first, publish flag, THEN dout ----
    float hv0[4], hv1[4];
    if (doL0){
      union { s16x4 v; _Float16 h[4]; } pu; pu.v = praw;
      #pragma unroll
      for (int j = 0; j < 4; ++j)
        hv0[j] = fast_tanh(s0v[j] + (float)pu.h[j]);
      i32x2 pk;
      pk[0] = (int)bf16rne(hv0[0]) | ((int)bf16rne(hv0[1]) << 16);
      pk[1] = (int)bf16rne(hv0[2]) | ((int)bf16rne(hv0[3]) << 16);
      st64_c(h0buf + (p&1)*65536 + eb*2048 + ecol*2, pk);
    }
    if (doL1){
      #pragma unroll
      for (int j = 0; j < 4; ++j)
        hv1[j] = fast_tanh(s1v[j] + bias1[j]);
      i32x2 pk;
      pk[0] = (int)bf16rne(hv1[0]) | ((int)bf16rne(hv1[1]) << 16);
      pk[1] = (int)bf16rne(hv1[2]) | ((int)bf16rne(hv1[3]) << 16);
      st64_c(h1buf + ((p-1)&1)*65536 + eb*2048 + ecol*2, pk);
    }

    vmem_drain();        // state stores visible
    __syncthreads();     // all waves' stores done
    if (tid == 0) st32_c(flags + rank, base + 2u + (unsigned)p);

    // ---- HBM outputs off the critical chain ----
    if (doL1){
      f32x4 o = {hv1[0], hv1[1], hv1[2], hv1[3]};
      *(f32x4*)(dout + (size_t)(p-1)*(NB*NH) + (size_t)eb*NH + ecol) = o;  // history
      if (p == T_SEQ)
        *(f32x4*)(dout + HIST_ELEMS + (size_t)NB*NH + (size_t)eb*NH + ecol) = o; // h_T layer1
    }
    if (doL0 && p == T_SEQ-1){
      f32x4 o = {hv0[0], hv0[1], hv0[2], hv0[3]};
      *(f32x4*)(dout + HIST_ELEMS + (size_t)eb*NH + ecol) = o;   // h_T layer0
    }
  }
}

extern "C" void kernel_launch(void* const* d_in, const int* in_sizes, int n_in,
                              void* d_out, int out_size, void* d_ws, size_t ws_size,
                              hipStream_t stream)
{
  (void)in_sizes; (void)n_in; (void)out_size;
  const float* x   = (const float*)d_in[0];
  const float* h0  = (const float*)d_in[1];
  const float* Wih = (const float*)d_in[2];
  const float* Whh = (const float*)d_in[3];
  const float* bih = (const float*)d_in[4];
  const float* bhh = (const float*)d_in[5];
  float* out = (float*)d_out;
  char*  ws  = (char*)d_ws;

  const size_t PRE0_OFF = (size_t)1 << 20;
  const size_t NEED = PRE0_OFF + (size_t)T_SEQ*NB*NH*sizeof(_Float16);
  if (ws_size < NEED) return;

  _Float16* pre0 = (_Float16*)(ws + PRE0_OFF);

  // reset ONLY the election area (flags at ws+4096 are a persistent epoch)
  hipMemsetAsync(ws, 0, 256, stream);
  pre_gemm<<<dim3(8, 512), 256, 0, stream>>>(x, Wih, bih, bhh, pre0);
  rnn_seq<<<dim3(512), 256, 0, stream>>>(h0, Wih, Whh, bih, bhh, pre0, out, ws);
}